// Round 14
// baseline (349.227 us; speedup 1.0000x reference)
//
#include <hip/hip_runtime.h>
#include <hip/hip_fp16.h>
#include <math.h>

#define BB 32
#define TT 100
#define VV 10000
#define DD 128
#define OUTN 1000
#define G3 384

// ---------------------------------------------------------------------------
// K0: one-shot weight conversion whh (f32) -> fp16 (unchanged)
// ---------------------------------------------------------------------------
__global__ __launch_bounds__(256) void k_w2h(
    const float* __restrict__ wf, const float* __restrict__ wb,
    __half* __restrict__ hf, __half* __restrict__ hb)
{
    const int i = blockIdx.x * 256 + threadIdx.x;   // grid covers 3*DD*DD
    hf[i] = __float2half(wf[i]);
    hb[i] = __float2half(wb[i]);
}

// ---------------------------------------------------------------------------
// K1: sparse embedding sum (unchanged)
// ---------------------------------------------------------------------------
__global__ __launch_bounds__(256) void k_embed(
    const float* __restrict__ x, const float* __restrict__ emb,
    float* __restrict__ e, int* __restrict__ mask)
{
    const int bt  = blockIdx.x;
    const int tid = threadIdx.x;
    __shared__ int   s_cnt;
    __shared__ int   s_any;
    __shared__ int   s_idx[256];
    __shared__ float s_val[256];
    if (tid == 0) { s_cnt = 0; s_any = 0; }
    __syncthreads();

    const float4* x4 = (const float4*)(x + (size_t)bt * VV);
    for (int i = tid; i < VV / 4; i += 256) {
        float4 v = x4[i];
        if (v.x != 0.f) { int p = atomicAdd(&s_cnt, 1); if (p < 256) { s_idx[p] = 4*i+0; s_val[p] = v.x; } }
        if (v.y != 0.f) { int p = atomicAdd(&s_cnt, 1); if (p < 256) { s_idx[p] = 4*i+1; s_val[p] = v.y; } }
        if (v.z != 0.f) { int p = atomicAdd(&s_cnt, 1); if (p < 256) { s_idx[p] = 4*i+2; s_val[p] = v.z; } }
        if (v.w != 0.f) { int p = atomicAdd(&s_cnt, 1); if (p < 256) { s_idx[p] = 4*i+3; s_val[p] = v.w; } }
    }
    __syncthreads();
    int cnt = s_cnt; if (cnt > 256) cnt = 256;
    if (tid < DD) {
        float a0 = 0.f, a1 = 0.f, a2 = 0.f, a3 = 0.f;
        int i = 0;
        for (; i + 3 < cnt; i += 4) {
            a0 += s_val[i+0] * emb[(size_t)s_idx[i+0] * DD + tid];
            a1 += s_val[i+1] * emb[(size_t)s_idx[i+1] * DD + tid];
            a2 += s_val[i+2] * emb[(size_t)s_idx[i+2] * DD + tid];
            a3 += s_val[i+3] * emb[(size_t)s_idx[i+3] * DD + tid];
        }
        for (; i < cnt; ++i)
            a0 += s_val[i] * emb[(size_t)s_idx[i] * DD + tid];
        float acc = (a0 + a1) + (a2 + a3);
        e[(size_t)bt * DD + tid] = acc;
        if (acc != 0.f) s_any = 1;
    }
    __syncthreads();
    if (tid == 0) mask[bt] = s_any;
}

// ---------------------------------------------------------------------------
// K2: input-side gates (unchanged)
// ---------------------------------------------------------------------------
__global__ __launch_bounds__(256) void k_gates(
    const float* __restrict__ e,
    const float* __restrict__ wih_f, const float* __restrict__ bih_f,
    const float* __restrict__ wih_b, const float* __restrict__ bih_b,
    float* __restrict__ x3)
{
    const int r0  = blockIdx.x * 8;
    const int tid = threadIdx.x;
    __shared__ __align__(16) float se[8][DD];
    for (int i = tid; i < 8 * DD; i += 256)
        se[i >> 7][i & 127] = e[(size_t)(r0 + (i >> 7)) * DD + (i & 127)];
    __syncthreads();

    for (int cc = 0; cc < 3; ++cc) {
        const int col = tid + cc * 256;
        const float* wrow;
        float bias;
        if (col < G3) { wrow = wih_f + (size_t)col * DD;        bias = bih_f[col]; }
        else          { wrow = wih_b + (size_t)(col - G3) * DD; bias = bih_b[col - G3]; }
        float acc[8];
        #pragma unroll
        for (int r = 0; r < 8; ++r) acc[r] = 0.f;
        const float4* w4 = (const float4*)wrow;
        for (int k4 = 0; k4 < DD / 4; ++k4) {
            float4 w = w4[k4];
            #pragma unroll
            for (int r = 0; r < 8; ++r) {
                float4 ev = *(const float4*)&se[r][4 * k4];
                acc[r] += ev.x * w.x + ev.y * w.y + ev.z * w.z + ev.w * w.w;
            }
        }
        #pragma unroll
        for (int r = 0; r < 8; ++r)
            x3[(size_t)(r0 + r) * 768 + col] = acc[r] + bias;
    }
}

// ---------------------------------------------------------------------------
typedef _Float16 h2v __attribute__((ext_vector_type(2)));
__device__ __forceinline__ h2v u2h2(unsigned u) { h2v h; __builtin_memcpy(&h, &u, 4); return h; }
__device__ __forceinline__ float2 h2f2(unsigned u)
{
    __half2 h = *reinterpret_cast<__half2*>(&u);
    return __half22float2(h);
}

#if __has_builtin(__builtin_amdgcn_fdot2)
#define DOT2(acc, wu, hu) acc = __builtin_amdgcn_fdot2(u2h2(wu), u2h2(hu), acc, false);
#else
#define DOT2(acc, wu, hu) { float2 wf_ = h2f2(wu); float2 hf_ = h2f2(hu); acc += wf_.x*hf_.x + wf_.y*hf_.y; }
#endif

// ---------------------------------------------------------------------------
// K3: GRU v13 — no-exchange, single-barrier step.
// R13 decomposition: v12's 570ns/step = DS ~384cyc + VALU ~100cyc + ~900cyc
// of BARRIER/PHASE overhead (2 barriers, p_lds exchange, tid<128 phase-2).
// v13 removes the structure cost: 128 thr/block, each thread g computes the
// FULL 128-k dot for its 3 gates (no partials, no p_lds, nonlinearity
// thread-local). fp16 weights streamed in-loop (3x128 halves/thread; v7
// proved streamed remat runs near the path floor); fp16 h broadcast (16
// uniform ds_read_b128/thread). h16 double-buffered => no WAR hazard => ONE
// barrier/step. Step ~= max(L1 stream 98KB ~768cyc, DS 384, VALU 384) ~=
// 330-370ns -> gru ~35-40us (from ~57). h recurrence stays fp32.
// Falsifier: total moves <5us -> all controllable floors reached -> ROOFLINE.
// ---------------------------------------------------------------------------
__global__ __launch_bounds__(128, 1) void k_gru(
    const float* __restrict__ x3,
    const __half* __restrict__ whh16_f, const float* __restrict__ bhh_f,
    const __half* __restrict__ whh16_b, const float* __restrict__ bhh_b,
    float* __restrict__ h_all)
{
    const int dir = blockIdx.x & 1;
    const int b   = blockIdx.x >> 1;
    const int g   = threadIdx.x;       // 0..127, owns output dim g
    const __half* whh = dir ? whh16_b : whh16_f;
    const float*  bhh = dir ? bhh_b  : bhh_f;

    const uint4* pr = (const uint4*)(whh + (size_t)(g         ) * DD);  // 16 uint4
    const uint4* pz = (const uint4*)(whh + (size_t)(DD     + g) * DD);
    const uint4* pn = (const uint4*)(whh + (size_t)(2 * DD + g) * DD);

    const float bhr = bhh[g], bhz = bhh[DD + g], bhn = bhh[2 * DD + g];

    __shared__ __align__(16) __half h16[2][DD];  // double-buffered fp16 h
    float h_reg = 0.f;
    h16[0][g] = __float2half(0.f);

    // prefetch x3 for t=0
    float xr, xz, xn;
    {
        const float* x3p = x3 + (size_t)(b * TT + (dir ? TT - 1 : 0)) * 768 + dir * G3;
        xr = x3p[g]; xz = x3p[DD + g]; xn = x3p[2 * DD + g];
    }
    __syncthreads();

    int cur = 0;
    for (int t = 0; t < TT; ++t) {
        const int te = dir ? (TT - 1 - t) : t;

        // prefetch x3 for t+1 (hidden under this step's dot)
        float nxr = 0.f, nxz = 0.f, nxn = 0.f;
        if (t + 1 < TT) {
            const int tn = dir ? (TT - 2 - t) : (t + 1);
            const float* x3n = x3 + (size_t)(b * TT + tn) * 768 + dir * G3;
            nxr = x3n[g]; nxz = x3n[DD + g]; nxn = x3n[2 * DD + g];
        }

        // full 128-k dot for gates r,z,n of dim g; 6 independent chains
        const __half* hc = h16[cur];
        float ar0 = 0.f, ar1 = 0.f, az0 = 0.f, az1 = 0.f, an0 = 0.f, an1 = 0.f;
        #pragma unroll
        for (int j = 0; j < 16; ++j) {
            const uint4 hv = *(const uint4*)&hc[8 * j];   // uniform addr: broadcast
            const uint4 wr = pr[j];
            const uint4 wz = pz[j];
            const uint4 wn = pn[j];
            DOT2(ar0, wr.x, hv.x) DOT2(ar1, wr.y, hv.y)
            DOT2(ar0, wr.z, hv.z) DOT2(ar1, wr.w, hv.w)
            DOT2(az0, wz.x, hv.x) DOT2(az1, wz.y, hv.y)
            DOT2(az0, wz.z, hv.z) DOT2(az1, wz.w, hv.w)
            DOT2(an0, wn.x, hv.x) DOT2(an1, wn.y, hv.y)
            DOT2(an0, wn.z, hv.z) DOT2(an1, wn.w, hv.w)
        }

        const float hr = ar0 + ar1 + bhr;
        const float hz = az0 + az1 + bhz;
        const float hn = an0 + an1 + bhn;
        const float r  = __builtin_amdgcn_rcpf(1.f + __expf(-(xr + hr)));
        const float z  = __builtin_amdgcn_rcpf(1.f + __expf(-(xz + hz)));
        // tanh(x) = 1 - 2/(e^(2x)+1): safe at +/-inf
        const float e2 = __expf(2.f * (xn + r * hn));
        const float n  = 1.f - 2.f * __builtin_amdgcn_rcpf(e2 + 1.f);
        const float hnew = n + z * (h_reg - n);          // == (1-z)*n + z*h
        h_reg = hnew;
        h16[cur ^ 1][g] = __float2half(hnew);            // write NEXT buffer (no WAR)
        h_all[(size_t)((dir * BB + b) * TT + te) * DD + g] = hnew;

        __syncthreads();                                  // single barrier per step
        cur ^= 1;
        xr = nxr; xz = nxz; xn = nxn;
    }
}

// ---------------------------------------------------------------------------
// K4a: per-batch attention + h_last + combine -> feat[b,128] (unchanged)
// ---------------------------------------------------------------------------
__global__ __launch_bounds__(256) void k_attn(
    const float* __restrict__ h_all, const int* __restrict__ mask,
    const float* __restrict__ attn_w, const float* __restrict__ attn_b,
    const float* __restrict__ comb_w, const float* __restrict__ comb_b,
    float* __restrict__ feat)
{
    const int b   = blockIdx.x;
    const int tid = threadIdx.x;
    __shared__ float s_aw[256];
    __shared__ float s_sc[128];
    __shared__ int   s_m[128];
    __shared__ float s_red[128];
    __shared__ __align__(16) float s_ch[512];

    s_aw[tid] = attn_w[tid];
    int m = 0;
    if (tid < 128) {
        m = (tid < TT) ? mask[b * TT + tid] : 0;
        s_m[tid] = m;
    }
    __syncthreads();
    for (int s = 64; s > 0; s >>= 1) {
        if (tid < s) s_m[tid] += s_m[tid + s];
        __syncthreads();
    }
    const int last = s_m[0] - 1;

    const float* hf = h_all + (size_t)(0 * BB + b) * TT * DD;
    const float* hb = h_all + (size_t)(1 * BB + b) * TT * DD;

    float sc = -1e9f;
    if (tid < TT) {
        float a = attn_b[0];
        const float4* hf4 = (const float4*)(hf + (size_t)tid * DD);
        const float4* hb4 = (const float4*)(hb + (size_t)tid * DD);
        for (int k = 0; k < DD / 4; ++k) {
            float4 v = hf4[k];
            a += v.x * s_aw[4*k] + v.y * s_aw[4*k+1] + v.z * s_aw[4*k+2] + v.w * s_aw[4*k+3];
        }
        for (int k = 0; k < DD / 4; ++k) {
            float4 v = hb4[k];
            a += v.x * s_aw[DD+4*k] + v.y * s_aw[DD+4*k+1] + v.z * s_aw[DD+4*k+2] + v.w * s_aw[DD+4*k+3];
        }
        sc = m ? a : -1e9f;
    }
    if (tid < 128) { s_sc[tid] = sc; s_red[tid] = sc; }
    __syncthreads();
    for (int s = 64; s > 0; s >>= 1) {
        if (tid < s) s_red[tid] = fmaxf(s_red[tid], s_red[tid + s]);
        __syncthreads();
    }
    const float mx = s_red[0];
    __syncthreads();
    float ex = 0.f;
    if (tid < 128) { ex = __expf(s_sc[tid] - mx); s_sc[tid] = ex; s_red[tid] = ex; }
    __syncthreads();
    for (int s = 64; s > 0; s >>= 1) {
        if (tid < s) s_red[tid] += s_red[tid + s];
        __syncthreads();
    }
    const float inv = 1.f / s_red[0];
    __syncthreads();

    {
        const int fl = tid & 127;
        const float* hp = (tid < 128) ? hf : hb;
        float csum = 0.f;
        for (int t = 0; t < TT; ++t)
            csum += s_sc[t] * hp[(size_t)t * DD + fl];
        s_ch[tid]       = csum * inv;
        s_ch[256 + tid] = hp[(size_t)last * DD + fl];
    }
    __syncthreads();

    if (tid < 128) {
        float a = comb_b[tid];
        const float4* cw = (const float4*)(comb_w + (size_t)tid * 512);
        for (int k = 0; k < 128; ++k) {
            float4 w4 = cw[k];
            float4 v4 = *(const float4*)&s_ch[4 * k];
            a += w4.x * v4.x + w4.y * v4.y + w4.z * v4.z + w4.w * v4.w;
        }
        feat[(size_t)b * DD + tid] = tanhf(a);
    }
}

// ---------------------------------------------------------------------------
// K4b: logits (unchanged)
// ---------------------------------------------------------------------------
__global__ __launch_bounds__(256) void k_logits(
    const float* __restrict__ feat, const float* __restrict__ fc_w,
    const float* __restrict__ fc_b, float* __restrict__ out)
{
    const int b   = blockIdx.x >> 2;
    const int oc  = blockIdx.x & 3;
    const int tid = threadIdx.x;
    const int o   = oc * 256 + tid;
    __shared__ __align__(16) float s_f[DD];
    if (tid < DD) s_f[tid] = feat[(size_t)b * DD + tid];
    __syncthreads();
    if (o < OUTN) {
        float a = fc_b[o];
        const float4* w4 = (const float4*)(fc_w + (size_t)o * DD);
        for (int k = 0; k < DD / 4; ++k) {
            float4 w = w4[k];
            float4 v = *(const float4*)&s_f[4 * k];
            a += w.x * v.x + w.y * v.y + w.z * v.z + w.w * v.w;
        }
        out[(size_t)b * OUTN + o] = a;
    }
}

// ---------------------------------------------------------------------------
extern "C" void kernel_launch(void* const* d_in, const int* in_sizes, int n_in,
                              void* d_out, int out_size, void* d_ws, size_t ws_size,
                              hipStream_t stream)
{
    const float* x      = (const float*)d_in[0];
    const float* emb    = (const float*)d_in[1];
    const float* wih_f  = (const float*)d_in[2];
    const float* whh_f  = (const float*)d_in[3];
    const float* bih_f  = (const float*)d_in[4];
    const float* bhh_f  = (const float*)d_in[5];
    const float* wih_b  = (const float*)d_in[6];
    const float* whh_b  = (const float*)d_in[7];
    const float* bih_b  = (const float*)d_in[8];
    const float* bhh_b  = (const float*)d_in[9];
    const float* attn_w = (const float*)d_in[10];
    const float* attn_b = (const float*)d_in[11];
    const float* comb_w = (const float*)d_in[12];
    const float* comb_b = (const float*)d_in[13];
    const float* fc_w   = (const float*)d_in[14];
    const float* fc_b   = (const float*)d_in[15];
    float* out = (float*)d_out;

    // workspace layout (floats)
    float*  ws      = (float*)d_ws;
    float*  e       = ws;                       // 409600
    float*  x3      = ws + 409600;              // 2457600
    float*  h_all   = ws + 2867200;             // 819200
    float*  feat    = ws + 3686400;             // 4096
    int*    mask    = (int*)(ws + 3690496);     // 3200
    __half* whh16_f = (__half*)(ws + 3693696);  // 49152 halves = 24576 floats
    __half* whh16_b = (__half*)(ws + 3718272);  // 49152 halves (total ~15 MB)

    k_w2h    <<<(3*DD*DD)/256, 256, 0, stream>>>(whh_f, whh_b, whh16_f, whh16_b);
    k_embed  <<<BB * TT,     256, 0, stream>>>(x, emb, e, mask);
    k_gates  <<<(BB * TT)/8, 256, 0, stream>>>(e, wih_f, bih_f, wih_b, bih_b, x3);
    k_gru    <<<2 * BB,      128, 0, stream>>>(x3, whh16_f, bhh_f, whh16_b, bhh_b, h_all);
    k_attn   <<<BB,          256, 0, stream>>>(h_all, mask, attn_w, attn_b, comb_w, comb_b, feat);
    k_logits <<<BB * 4,      256, 0, stream>>>(feat, fc_w, fc_b, out);
}

// Round 15
// 340.720 us; speedup vs baseline: 1.0250x; 1.0250x over previous
//
#include <hip/hip_runtime.h>
#include <hip/hip_fp16.h>
#include <math.h>

#define BB 32
#define TT 100
#define VV 10000
#define DD 128
#define OUTN 1000
#define G3 384

// ---------------------------------------------------------------------------
// K0: one-shot weight conversion whh (f32) -> fp16
// ---------------------------------------------------------------------------
__global__ __launch_bounds__(256) void k_w2h(
    const float* __restrict__ wf, const float* __restrict__ wb,
    __half* __restrict__ hf, __half* __restrict__ hb)
{
    const int i = blockIdx.x * 256 + threadIdx.x;   // grid covers 3*DD*DD
    hf[i] = __float2half(wf[i]);
    hb[i] = __float2half(wb[i]);
}

// ---------------------------------------------------------------------------
// K1: sparse embedding sum
// ---------------------------------------------------------------------------
__global__ __launch_bounds__(256) void k_embed(
    const float* __restrict__ x, const float* __restrict__ emb,
    float* __restrict__ e, int* __restrict__ mask)
{
    const int bt  = blockIdx.x;
    const int tid = threadIdx.x;
    __shared__ int   s_cnt;
    __shared__ int   s_any;
    __shared__ int   s_idx[256];
    __shared__ float s_val[256];
    if (tid == 0) { s_cnt = 0; s_any = 0; }
    __syncthreads();

    const float4* x4 = (const float4*)(x + (size_t)bt * VV);
    for (int i = tid; i < VV / 4; i += 256) {
        float4 v = x4[i];
        if (v.x != 0.f) { int p = atomicAdd(&s_cnt, 1); if (p < 256) { s_idx[p] = 4*i+0; s_val[p] = v.x; } }
        if (v.y != 0.f) { int p = atomicAdd(&s_cnt, 1); if (p < 256) { s_idx[p] = 4*i+1; s_val[p] = v.y; } }
        if (v.z != 0.f) { int p = atomicAdd(&s_cnt, 1); if (p < 256) { s_idx[p] = 4*i+2; s_val[p] = v.z; } }
        if (v.w != 0.f) { int p = atomicAdd(&s_cnt, 1); if (p < 256) { s_idx[p] = 4*i+3; s_val[p] = v.w; } }
    }
    __syncthreads();
    int cnt = s_cnt; if (cnt > 256) cnt = 256;
    if (tid < DD) {
        float a0 = 0.f, a1 = 0.f, a2 = 0.f, a3 = 0.f;
        int i = 0;
        for (; i + 3 < cnt; i += 4) {
            a0 += s_val[i+0] * emb[(size_t)s_idx[i+0] * DD + tid];
            a1 += s_val[i+1] * emb[(size_t)s_idx[i+1] * DD + tid];
            a2 += s_val[i+2] * emb[(size_t)s_idx[i+2] * DD + tid];
            a3 += s_val[i+3] * emb[(size_t)s_idx[i+3] * DD + tid];
        }
        for (; i < cnt; ++i)
            a0 += s_val[i] * emb[(size_t)s_idx[i] * DD + tid];
        float acc = (a0 + a1) + (a2 + a3);
        e[(size_t)bt * DD + tid] = acc;
        if (acc != 0.f) s_any = 1;
    }
    __syncthreads();
    if (tid == 0) mask[bt] = s_any;
}

// ---------------------------------------------------------------------------
// K2: input-side gates
// ---------------------------------------------------------------------------
__global__ __launch_bounds__(256) void k_gates(
    const float* __restrict__ e,
    const float* __restrict__ wih_f, const float* __restrict__ bih_f,
    const float* __restrict__ wih_b, const float* __restrict__ bih_b,
    float* __restrict__ x3)
{
    const int r0  = blockIdx.x * 8;
    const int tid = threadIdx.x;
    __shared__ __align__(16) float se[8][DD];
    for (int i = tid; i < 8 * DD; i += 256)
        se[i >> 7][i & 127] = e[(size_t)(r0 + (i >> 7)) * DD + (i & 127)];
    __syncthreads();

    for (int cc = 0; cc < 3; ++cc) {
        const int col = tid + cc * 256;
        const float* wrow;
        float bias;
        if (col < G3) { wrow = wih_f + (size_t)col * DD;        bias = bih_f[col]; }
        else          { wrow = wih_b + (size_t)(col - G3) * DD; bias = bih_b[col - G3]; }
        float acc[8];
        #pragma unroll
        for (int r = 0; r < 8; ++r) acc[r] = 0.f;
        const float4* w4 = (const float4*)wrow;
        for (int k4 = 0; k4 < DD / 4; ++k4) {
            float4 w = w4[k4];
            #pragma unroll
            for (int r = 0; r < 8; ++r) {
                float4 ev = *(const float4*)&se[r][4 * k4];
                acc[r] += ev.x * w.x + ev.y * w.y + ev.z * w.z + ev.w * w.w;
            }
        }
        #pragma unroll
        for (int r = 0; r < 8; ++r)
            x3[(size_t)(r0 + r) * 768 + col] = acc[r] + bias;
    }
}

// ---------------------------------------------------------------------------
// asm global load (asm-defined => not rematerializable)
// ---------------------------------------------------------------------------
__device__ __forceinline__ uint4 ld_pin_u128(const uint4* p)
{
    uint4 r;
    asm volatile("global_load_dwordx4 %0, %1, off" : "=v"(r) : "v"(p));
    return r;
}

typedef _Float16 h2v __attribute__((ext_vector_type(2)));
__device__ __forceinline__ h2v u2h2(unsigned u) { h2v h; __builtin_memcpy(&h, &u, 4); return h; }
__device__ __forceinline__ float2 h2f2(unsigned u)
{
    __half2 h = *reinterpret_cast<__half2*>(&u);
    return __half22float2(h);
}

#if __has_builtin(__builtin_amdgcn_fdot2)
#define DOT2(acc, wu, hu) acc = __builtin_amdgcn_fdot2(u2h2(wu), u2h2(hu), acc, false);
#else
#define DOT2(acc, wu, hu) { float2 wf_ = h2f2(wu); float2 hf_ = h2f2(hu); acc += wf_.x*hf_.x + wf_.y*hf_.y; }
#endif

// ---------------------------------------------------------------------------
// K3: GRU v12 — FINAL (measured best: total 338.6us, R13).
// 512 thr = (g x kq), 64 blocks, fp16 weights (48 VGPR preload) + fp16
// h-broadcast (32 ds_read_b128/step) + dot2 + 2-barrier exchange.
// R14 lesson: v13's "no-exchange single-barrier" at 128 thr (2 waves)
// REGRESSED +10.6us — 2 waves can't hide the in-loop weight-stream latency;
// the exchange structure is overlapped wave-parallel work, not pure serial
// cost. v12's 8-wave 2-barrier balance is the measured optimum.
// Ledger: residency x10 refused; weight fp16 -3us; h fp16 -12us (kept);
// exchange-removal +10.6 (reverted); pairing/fusion (reverted).
// ---------------------------------------------------------------------------
__global__ __launch_bounds__(512, 1) void k_gru(
    const float* __restrict__ x3,
    const __half* __restrict__ whh16_f, const float* __restrict__ bhh_f,
    const __half* __restrict__ whh16_b, const float* __restrict__ bhh_b,
    float* __restrict__ h_all)
{
    const int dir = blockIdx.x & 1;
    const int b   = blockIdx.x >> 1;
    const int tid = threadIdx.x;       // 0..511
    const int g   = tid & 127;         // output dim
    const int kq  = tid >> 7;          // k-quarter: 0..3
    const int kb  = kq * 32;           // k base (elements)
    const __half* whh = dir ? whh16_b : whh16_f;
    const float*  bhh = dir ? bhh_b  : bhh_f;

    const uint4* pr4 = (const uint4*)(whh + (size_t)(g         ) * DD + kb);
    const uint4* pz4 = (const uint4*)(whh + (size_t)(DD     + g) * DD + kb);
    const uint4* pn4 = (const uint4*)(whh + (size_t)(2 * DD + g) * DD + kb);

#define Q4(M) M(0) M(1) M(2) M(3)
    // 12 uint4 = 96 halves (48 VGPRs)
#define DECLW(j) uint4 wr##j = ld_pin_u128(pr4 + (j)); \
                 uint4 wz##j = ld_pin_u128(pz4 + (j)); \
                 uint4 wn##j = ld_pin_u128(pn4 + (j));
    Q4(DECLW)
#undef DECLW
    asm volatile("s_waitcnt vmcnt(0)" ::: "memory");
    __builtin_amdgcn_sched_barrier(0);

    float bhr = 0.f, bhz = 0.f, bhn = 0.f;
    if (tid < DD) { bhr = bhh[g]; bhz = bhh[DD + g]; bhn = bhh[2 * DD + g]; }

    __shared__ __align__(16) __half h16[DD];   // fp16 broadcast copy of h
    __shared__ float p_lds[9 * DD];            // [(kq-1)*3 + gate][g]
    float h_reg = 0.f;
    if (tid < DD) h16[tid] = __float2half(0.f);

    // prefetch x3 for t=0
    float xr = 0.f, xz = 0.f, xn = 0.f;
    {
        const float* x3p = x3 + (size_t)(b * TT + (dir ? TT - 1 : 0)) * 768 + dir * G3;
        if (tid < DD) { xr = x3p[g]; xz = x3p[DD + g]; xn = x3p[2 * DD + g]; }
    }
    __syncthreads();

    for (int t = 0; t < TT; ++t) {
        const int te = dir ? (TT - 1 - t) : t;

        // prefetch x3 for t+1 (hidden under this step's dot + barriers)
        float nxr = 0.f, nxz = 0.f, nxn = 0.f;
        if (t + 1 < TT) {
            const int tn = dir ? (TT - 2 - t) : (t + 1);
            const float* x3n = x3 + (size_t)(b * TT + tn) * 768 + dir * G3;
            if (tid < DD) { nxr = x3n[g]; nxz = x3n[DD + g]; nxn = x3n[2 * DD + g]; }
        }

        // partial dots over this thread's k-quarter; one b128 = 8 h values
        float ar0 = 0.f, ar1 = 0.f, az0 = 0.f, az1 = 0.f, an0 = 0.f, an1 = 0.f;
#define FMA8(j) { \
        const uint4 hv = *(const uint4*)&h16[kb + 8 * (j)]; \
        DOT2(ar0, wr##j.x, hv.x) DOT2(ar1, wr##j.y, hv.y) \
        DOT2(ar0, wr##j.z, hv.z) DOT2(ar1, wr##j.w, hv.w) \
        DOT2(az0, wz##j.x, hv.x) DOT2(az1, wz##j.y, hv.y) \
        DOT2(az0, wz##j.z, hv.z) DOT2(az1, wz##j.w, hv.w) \
        DOT2(an0, wn##j.x, hv.x) DOT2(an1, wn##j.y, hv.y) \
        DOT2(an0, wn##j.z, hv.z) DOT2(an1, wn##j.w, hv.w) }
        Q4(FMA8)
#undef FMA8
        const float pr = ar0 + ar1, pz = az0 + az1, pn = an0 + an1;

        if (kq) {
            const int q = (kq - 1) * 3;
            p_lds[(q + 0) * DD + g] = pr;
            p_lds[(q + 1) * DD + g] = pz;
            p_lds[(q + 2) * DD + g] = pn;
        }
        __syncthreads();

        if (tid < DD) {
            float hr = pr + p_lds[0*DD+g] + p_lds[3*DD+g] + p_lds[6*DD+g] + bhr;
            float hz = pz + p_lds[1*DD+g] + p_lds[4*DD+g] + p_lds[7*DD+g] + bhz;
            float hn = pn + p_lds[2*DD+g] + p_lds[5*DD+g] + p_lds[8*DD+g] + bhn;
            float r  = __builtin_amdgcn_rcpf(1.f + __expf(-(xr + hr)));
            float z  = __builtin_amdgcn_rcpf(1.f + __expf(-(xz + hz)));
            // tanh(x) = 1 - 2/(e^(2x)+1): safe at +/-inf
            float e2 = __expf(2.f * (xn + r * hn));
            float n  = 1.f - 2.f * __builtin_amdgcn_rcpf(e2 + 1.f);
            float hnew = n + z * (h_reg - n);            // == (1-z)*n + z*h
            h_reg = hnew;
            h16[g] = __float2half(hnew);
            h_all[(size_t)((dir * BB + b) * TT + te) * DD + g] = hnew;
        }
        __syncthreads();
        xr = nxr; xz = nxz; xn = nxn;
    }
#undef Q4
}

// ---------------------------------------------------------------------------
// K4a: per-batch attention + h_last + combine -> feat[b,128]
// ---------------------------------------------------------------------------
__global__ __launch_bounds__(256) void k_attn(
    const float* __restrict__ h_all, const int* __restrict__ mask,
    const float* __restrict__ attn_w, const float* __restrict__ attn_b,
    const float* __restrict__ comb_w, const float* __restrict__ comb_b,
    float* __restrict__ feat)
{
    const int b   = blockIdx.x;
    const int tid = threadIdx.x;
    __shared__ float s_aw[256];
    __shared__ float s_sc[128];
    __shared__ int   s_m[128];
    __shared__ float s_red[128];
    __shared__ __align__(16) float s_ch[512];

    s_aw[tid] = attn_w[tid];
    int m = 0;
    if (tid < 128) {
        m = (tid < TT) ? mask[b * TT + tid] : 0;
        s_m[tid] = m;
    }
    __syncthreads();
    for (int s = 64; s > 0; s >>= 1) {
        if (tid < s) s_m[tid] += s_m[tid + s];
        __syncthreads();
    }
    const int last = s_m[0] - 1;

    const float* hf = h_all + (size_t)(0 * BB + b) * TT * DD;
    const float* hb = h_all + (size_t)(1 * BB + b) * TT * DD;

    float sc = -1e9f;
    if (tid < TT) {
        float a = attn_b[0];
        const float4* hf4 = (const float4*)(hf + (size_t)tid * DD);
        const float4* hb4 = (const float4*)(hb + (size_t)tid * DD);
        for (int k = 0; k < DD / 4; ++k) {
            float4 v = hf4[k];
            a += v.x * s_aw[4*k] + v.y * s_aw[4*k+1] + v.z * s_aw[4*k+2] + v.w * s_aw[4*k+3];
        }
        for (int k = 0; k < DD / 4; ++k) {
            float4 v = hb4[k];
            a += v.x * s_aw[DD+4*k] + v.y * s_aw[DD+4*k+1] + v.z * s_aw[DD+4*k+2] + v.w * s_aw[DD+4*k+3];
        }
        sc = m ? a : -1e9f;
    }
    if (tid < 128) { s_sc[tid] = sc; s_red[tid] = sc; }
    __syncthreads();
    for (int s = 64; s > 0; s >>= 1) {
        if (tid < s) s_red[tid] = fmaxf(s_red[tid], s_red[tid + s]);
        __syncthreads();
    }
    const float mx = s_red[0];
    __syncthreads();
    float ex = 0.f;
    if (tid < 128) { ex = __expf(s_sc[tid] - mx); s_sc[tid] = ex; s_red[tid] = ex; }
    __syncthreads();
    for (int s = 64; s > 0; s >>= 1) {
        if (tid < s) s_red[tid] += s_red[tid + s];
        __syncthreads();
    }
    const float inv = 1.f / s_red[0];
    __syncthreads();

    {
        const int fl = tid & 127;
        const float* hp = (tid < 128) ? hf : hb;
        float csum = 0.f;
        for (int t = 0; t < TT; ++t)
            csum += s_sc[t] * hp[(size_t)t * DD + fl];
        s_ch[tid]       = csum * inv;
        s_ch[256 + tid] = hp[(size_t)last * DD + fl];
    }
    __syncthreads();

    if (tid < 128) {
        float a = comb_b[tid];
        const float4* cw = (const float4*)(comb_w + (size_t)tid * 512);
        for (int k = 0; k < 128; ++k) {
            float4 w4 = cw[k];
            float4 v4 = *(const float4*)&s_ch[4 * k];
            a += w4.x * v4.x + w4.y * v4.y + w4.z * v4.z + w4.w * v4.w;
        }
        feat[(size_t)b * DD + tid] = tanhf(a);
    }
}

// ---------------------------------------------------------------------------
// K4b: logits
// ---------------------------------------------------------------------------
__global__ __launch_bounds__(256) void k_logits(
    const float* __restrict__ feat, const float* __restrict__ fc_w,
    const float* __restrict__ fc_b, float* __restrict__ out)
{
    const int b   = blockIdx.x >> 2;
    const int oc  = blockIdx.x & 3;
    const int tid = threadIdx.x;
    const int o   = oc * 256 + tid;
    __shared__ __align__(16) float s_f[DD];
    if (tid < DD) s_f[tid] = feat[(size_t)b * DD + tid];
    __syncthreads();
    if (o < OUTN) {
        float a = fc_b[o];
        const float4* w4 = (const float4*)(fc_w + (size_t)o * DD);
        for (int k = 0; k < DD / 4; ++k) {
            float4 w = w4[k];
            float4 v = *(const float4*)&s_f[4 * k];
            a += w.x * v.x + w.y * v.y + w.z * v.z + w.w * v.w;
        }
        out[(size_t)b * OUTN + o] = a;
    }
}

// ---------------------------------------------------------------------------
extern "C" void kernel_launch(void* const* d_in, const int* in_sizes, int n_in,
                              void* d_out, int out_size, void* d_ws, size_t ws_size,
                              hipStream_t stream)
{
    const float* x      = (const float*)d_in[0];
    const float* emb    = (const float*)d_in[1];
    const float* wih_f  = (const float*)d_in[2];
    const float* whh_f  = (const float*)d_in[3];
    const float* bih_f  = (const float*)d_in[4];
    const float* bhh_f  = (const float*)d_in[5];
    const float* wih_b  = (const float*)d_in[6];
    const float* whh_b  = (const float*)d_in[7];
    const float* bih_b  = (const float*)d_in[8];
    const float* bhh_b  = (const float*)d_in[9];
    const float* attn_w = (const float*)d_in[10];
    const float* attn_b = (const float*)d_in[11];
    const float* comb_w = (const float*)d_in[12];
    const float* comb_b = (const float*)d_in[13];
    const float* fc_w   = (const float*)d_in[14];
    const float* fc_b   = (const float*)d_in[15];
    float* out = (float*)d_out;

    // workspace layout (floats)
    float*  ws      = (float*)d_ws;
    float*  e       = ws;                       // 409600
    float*  x3      = ws + 409600;              // 2457600
    float*  h_all   = ws + 2867200;             // 819200
    float*  feat    = ws + 3686400;             // 4096
    int*    mask    = (int*)(ws + 3690496);     // 3200
    __half* whh16_f = (__half*)(ws + 3693696);  // 49152 halves = 24576 floats
    __half* whh16_b = (__half*)(ws + 3718272);  // 49152 halves (total ~15 MB)

    k_w2h    <<<(3*DD*DD)/256, 256, 0, stream>>>(whh_f, whh_b, whh16_f, whh16_b);
    k_embed  <<<BB * TT,     256, 0, stream>>>(x, emb, e, mask);
    k_gates  <<<(BB * TT)/8, 256, 0, stream>>>(e, wih_f, bih_f, wih_b, bih_b, x3);
    k_gru    <<<2 * BB,      512, 0, stream>>>(x3, whh16_f, bhh_f, whh16_b, bhh_b, h_all);
    k_attn   <<<BB,          256, 0, stream>>>(h_all, mask, attn_w, attn_b, comb_w, comb_b, feat);
    k_logits <<<BB * 4,      256, 0, stream>>>(feat, fc_w, fc_b, out);
}